// Round 7
// baseline (358.411 us; speedup 1.0000x reference)
//
#include <hip/hip_runtime.h>

// (B,C,H,W) = (8,21,512,512), gamma = 2.0
#define CCH    21
#define HWSZ   (512*512)          // 2^18
#define HW4    (HWSZ/4)           // 2^16 float4 groups per plane
#define NPIX   (8*HWSZ)           // 2097152
#define BLKT   256
#define NBLK   (NPIX/4/BLKT)      // 2048 blocks, one float4 (4 pixels) per thread
#define CB     3                  // channels per staged batch (21 = 7*3)
#define NBATCH (CCH/CB)           // 7

// s_waitcnt imm: lgkmcnt=15 (don't care), expcnt=7 (don't care), vmcnt=N
#define WAIT_VM6() __builtin_amdgcn_s_waitcnt(0x0F70 | 6)
#define WAIT_VM0() __builtin_amdgcn_s_waitcnt(0x0F70 | 0)

typedef float vfloat4 __attribute__((ext_vector_type(4)));

// async global->LDS, 16 B per lane; lds dest is wave-uniform base + lane*16
__device__ __forceinline__ void stage16(const float* g, vfloat4* l) {
    __builtin_amdgcn_global_load_lds(
        (const __attribute__((address_space(1))) unsigned int*)g,
        (__attribute__((address_space(3))) unsigned int*)l, 16, 0, 0);
}

// ---------------------------------------------------------------------------
// Kernel 1: single-pass focal term, global_load_lds-staged.
// Per batch: 3 channels x (pred+targ) -> 24 KB/block, double-buffered (48 KB
// -> 3 blocks/CU, 12 waves/CU). Each wave stages ONLY its own 64-lane slice
// and reads back ONLY what it staged: no __syncthreads in the K-loop, just
// per-wave s_waitcnt vmcnt(6) (batch k's 6 loads done; batch k+1's 6 still
// in flight). This decouples outstanding-load capacity from VGPRs/writeback
// (R2-R6 register-based variants all plateaued at ~3.5 TB/s effective read).
// No max-subtraction: logits are N(0,1), fp32 exp cannot overflow; error
// budget ~2% relative.
// ---------------------------------------------------------------------------
__global__ __launch_bounds__(BLKT) void cb_focal_partial(
    const float* __restrict__ pred, const float* __restrict__ targ,
    float* __restrict__ gsum, float* __restrict__ gcnt)
{
    __shared__ vfloat4 sbuf[2][2*CB][BLKT];    // 2*6*256*16B = 48 KB
    __shared__ float ls_sum[CCH];
    __shared__ float ls_cnt[CCH];
    if (threadIdx.x < CCH) { ls_sum[threadIdx.x] = 0.f; ls_cnt[threadIdx.x] = 0.f; }
    __syncthreads();

    const int tid = blockIdx.x * BLKT + threadIdx.x;   // 0 .. 524287
    const int b   = tid >> 16;                         // / HW4
    const int hw4 = tid & (HW4 - 1);
    const float* pp = pred + (size_t)b * CCH * HWSZ + (size_t)hw4 * 4;
    const float* tp = targ + (size_t)b * CCH * HWSZ + (size_t)hw4 * 4;
    const int wv = threadIdx.x & 192;                  // wave base: 0,64,128,192

    float s0 = 0.f, s1 = 0.f, s2 = 0.f, s3 = 0.f;
    float vy0 = 0.f, vy1 = 0.f, vy2 = 0.f, vy3 = 0.f;
    float ey0 = 1.f, ey1 = 1.f, ey2 = 1.f, ey3 = 1.f;
    int   y0 = 0, y1 = 0, y2 = 0, y3 = 0;

    auto issue = [&](int k, int buf) {
        #pragma unroll
        for (int j = 0; j < CB; ++j) {
            const size_t coff = (size_t)(k * CB + j) * HWSZ;
            stage16(pp + coff, &sbuf[buf][2*j    ][wv]);
            stage16(tp + coff, &sbuf[buf][2*j + 1][wv]);
        }
    };

    auto compute = [&](int k) {
        #pragma unroll
        for (int j = 0; j < CB; ++j) {
            const vfloat4 v = sbuf[k & 1][2*j    ][threadIdx.x];
            const vfloat4 t = sbuf[k & 1][2*j + 1][threadIdx.x];
            const int c = k * CB + j;
            const float e0 = __expf(v.x), e1 = __expf(v.y),
                        e2 = __expf(v.z), e3 = __expf(v.w);
            s0 += e0; s1 += e1; s2 += e2; s3 += e3;
            const bool h0 = t.x > 0.5f, h1 = t.y > 0.5f,
                       h2 = t.z > 0.5f, h3 = t.w > 0.5f;
            y0 = h0 ? c : y0;  vy0 = h0 ? v.x : vy0;  ey0 = h0 ? e0 : ey0;
            y1 = h1 ? c : y1;  vy1 = h1 ? v.y : vy1;  ey1 = h1 ? e1 : ey1;
            y2 = h2 ? c : y2;  vy2 = h2 ? v.z : vy2;  ey2 = h2 ? e2 : ey2;
            y3 = h3 ? c : y3;  vy3 = h3 ? v.w : vy3;  ey3 = h3 ? e3 : ey3;
        }
    };

    issue(0, 0);
    #pragma unroll
    for (int k = 0; k < NBATCH - 1; ++k) {
        issue(k + 1, (k + 1) & 1);
        __builtin_amdgcn_sched_barrier(0);
        WAIT_VM6();                        // batch k's 6 loads complete
        __builtin_amdgcn_sched_barrier(0);
        compute(k);
    }
    __builtin_amdgcn_sched_barrier(0);
    WAIT_VM0();
    __builtin_amdgcn_sched_barrier(0);
    compute(NBATCH - 1);

    // rv = (1 - p_y)^2 * log p_y ;  p_y = e_y / s ;  log p_y = v_y - log s
    {
        const float l0 = vy0 - __logf(s0), p0 = ey0 / s0, o0 = 1.f - p0;
        const float l1 = vy1 - __logf(s1), p1 = ey1 / s1, o1 = 1.f - p1;
        const float l2 = vy2 - __logf(s2), p2 = ey2 / s2, o2 = 1.f - p2;
        const float l3 = vy3 - __logf(s3), p3 = ey3 / s3, o3 = 1.f - p3;
        atomicAdd(&ls_sum[y0], o0 * o0 * l0);  atomicAdd(&ls_cnt[y0], 1.f);
        atomicAdd(&ls_sum[y1], o1 * o1 * l1);  atomicAdd(&ls_cnt[y1], 1.f);
        atomicAdd(&ls_sum[y2], o2 * o2 * l2);  atomicAdd(&ls_cnt[y2], 1.f);
        atomicAdd(&ls_sum[y3], o3 * o3 * l3);  atomicAdd(&ls_cnt[y3], 1.f);
    }
    __syncthreads();
    if (threadIdx.x < CCH) {
        atomicAdd(&gsum[threadIdx.x], ls_sum[threadIdx.x]);
        atomicAdd(&gcnt[threadIdx.x], ls_cnt[threadIdx.x]);
    }
}

// ---------------------------------------------------------------------------
// Kernel 2: one wave. Class-balanced weights + final scalar, in double.
// ---------------------------------------------------------------------------
__global__ void cb_focal_final(const float* __restrict__ gsum,
                               const float* __restrict__ gcnt,
                               float* __restrict__ out)
{
    const int lane = threadIdx.x;
    double term = 0.0;
    if (lane < CCH) {
        const double n    = (double)NPIX;
        const double beta = (n - 1.0) / n;
        const double w = (1.0 - beta) / (1.0 - pow(beta, (double)gcnt[lane]) + 1e-6);
        term = w * (double)gsum[lane];
    }
    for (int off = 32; off; off >>= 1) term += __shfl_down(term, off, 64);
    if (lane == 0) out[0] = (float)(-term / (double)NPIX);
}

// ---------------------------------------------------------------------------
extern "C" void kernel_launch(void* const* d_in, const int* in_sizes, int n_in,
                              void* d_out, int out_size, void* d_ws, size_t ws_size,
                              hipStream_t stream) {
    const float* pred = (const float*)d_in[0];
    const float* targ = (const float*)d_in[1];
    float* out  = (float*)d_out;
    float* gsum = (float*)d_ws;          // [21]
    float* gcnt = gsum + CCH;            // [21]

    (void)hipMemsetAsync(gsum, 0, 2 * CCH * sizeof(float), stream);
    cb_focal_partial<<<NBLK, BLKT, 0, stream>>>(pred, targ, gsum, gcnt);
    cb_focal_final<<<1, 64, 0, stream>>>(gsum, gcnt, out);
}

// Round 8
// 345.731 us; speedup vs baseline: 1.0367x; 1.0367x over previous
//
#include <hip/hip_runtime.h>

// (B,C,H,W) = (8,21,512,512), gamma = 2.0
#define CCH    21
#define HWSZ   (512*512)          // 2^18
#define HW4    (HWSZ/4)           // 2^16 float4 groups per plane
#define NPIX   (8*HWSZ)           // 2097152
#define BLKT   256
#define NBLK   (NPIX/4/BLKT)      // 2048 blocks, one float4 (4 pixels) per thread
#define CB     7                  // channels per batch (21 = 3*7)
#define NB     3                  // batches

// s_waitcnt imm: lgkmcnt=15 (don't care), expcnt=7 (don't care), vmcnt=N
#define WAIT_VM(n) __builtin_amdgcn_s_waitcnt(0x0F70 | (n))

typedef float vfloat4 __attribute__((ext_vector_type(4)));

// async global->LDS, 16 B per lane; lds dest is wave-uniform base + lane*16
__device__ __forceinline__ void stage16(const float* g, vfloat4* l) {
    __builtin_amdgcn_global_load_lds(
        (const __attribute__((address_space(1))) unsigned int*)g,
        (__attribute__((address_space(3))) unsigned int*)l, 16, 0, 0);
}

// ---------------------------------------------------------------------------
// Kernel 1: single-pass focal term, DUAL-PATH streaming.
//   pred -> nt register loads (R6's fastest structure)
//   targ -> global_load_lds DMA (R7's structure), double-buffered
// Both streams pipelined one batch ahead per-wave; single FIFO vmcnt(14)
// fence per iteration (7 DMA + 7 reg loads of batch k+1 stay in flight while
// batch k is consumed). No __syncthreads in the K-loop — each wave stages and
// reads back only its own 64-lane LDS slice.
// Discriminating experiment: R1-R7 all plateau at ~11-14 delivered B/cyc/CU
// regardless of source (L3-resident replay = same time as HBM), implicating
// per-CU outstanding-read tracking. If the register and LDS-DMA paths have
// separate trackers, the caps add; if shared, this is flat and ~3.5 TB/s is
// the structural read ceiling.
// No max-subtraction: logits are N(0,1), fp32 exp cannot overflow; error
// budget ~2% relative.
// ---------------------------------------------------------------------------
__global__ __launch_bounds__(BLKT) void cb_focal_partial(
    const float* __restrict__ pred, const float* __restrict__ targ,
    float* __restrict__ gsum, float* __restrict__ gcnt)
{
    __shared__ vfloat4 tbuf[2][CB][BLKT];      // 2*7*256*16 B = 56 KB
    __shared__ float ls_sum[CCH];
    __shared__ float ls_cnt[CCH];
    if (threadIdx.x < CCH) { ls_sum[threadIdx.x] = 0.f; ls_cnt[threadIdx.x] = 0.f; }
    __syncthreads();

    const int tid = blockIdx.x * BLKT + threadIdx.x;   // 0 .. 524287
    const int b   = tid >> 16;                         // / HW4
    const int hw4 = tid & (HW4 - 1);
    const float* pp = pred + (size_t)b * CCH * HWSZ + (size_t)hw4 * 4;
    const float* tp = targ + (size_t)b * CCH * HWSZ + (size_t)hw4 * 4;
    const int wv = threadIdx.x & 192;                  // wave base: 0,64,128,192

    float s0 = 0.f, s1 = 0.f, s2 = 0.f, s3 = 0.f;
    float vy0 = 0.f, vy1 = 0.f, vy2 = 0.f, vy3 = 0.f;
    float ey0 = 1.f, ey1 = 1.f, ey2 = 1.f, ey3 = 1.f;
    int   y0 = 0, y1 = 0, y2 = 0, y3 = 0;

    vfloat4 v[2][CB];                                  // pred double-buffer (regs)

    // ---- prologue: batch 0 in flight (7 DMA + 7 reg nt loads) ----
    #pragma unroll
    for (int j = 0; j < CB; ++j)
        stage16(tp + (size_t)j * HWSZ, &tbuf[0][j][wv]);
    #pragma unroll
    for (int j = 0; j < CB; ++j)
        v[0][j] = __builtin_nontemporal_load((const vfloat4*)(pp + (size_t)j * HWSZ));
    __builtin_amdgcn_sched_barrier(0);

    #pragma unroll
    for (int kk = 0; kk < NB; ++kk) {
        if (kk + 1 < NB) {
            // issue batch kk+1: 7 DMA then 7 reg loads (14 newest vmcnt slots)
            #pragma unroll
            for (int j = 0; j < CB; ++j)
                stage16(tp + (size_t)((kk + 1) * CB + j) * HWSZ,
                        &tbuf[(kk + 1) & 1][j][wv]);
            #pragma unroll
            for (int j = 0; j < CB; ++j)
                v[(kk + 1) & 1][j] = __builtin_nontemporal_load(
                    (const vfloat4*)(pp + (size_t)((kk + 1) * CB + j) * HWSZ));
            __builtin_amdgcn_sched_barrier(0);
            WAIT_VM(14);                   // batch kk's 14 ops complete
        } else {
            __builtin_amdgcn_sched_barrier(0);
            WAIT_VM(0);
        }
        __builtin_amdgcn_sched_barrier(0);

        // ---- consume batch kk ----
        #pragma unroll
        for (int j = 0; j < CB; ++j) {
            const vfloat4 pv = v[kk & 1][j];
            const vfloat4 t  = tbuf[kk & 1][j][threadIdx.x];
            const int c = kk * CB + j;
            const float e0 = __expf(pv.x), e1 = __expf(pv.y),
                        e2 = __expf(pv.z), e3 = __expf(pv.w);
            s0 += e0; s1 += e1; s2 += e2; s3 += e3;
            const bool h0 = t.x > 0.5f, h1 = t.y > 0.5f,
                       h2 = t.z > 0.5f, h3 = t.w > 0.5f;
            y0 = h0 ? c : y0;  vy0 = h0 ? pv.x : vy0;  ey0 = h0 ? e0 : ey0;
            y1 = h1 ? c : y1;  vy1 = h1 ? pv.y : vy1;  ey1 = h1 ? e1 : ey1;
            y2 = h2 ? c : y2;  vy2 = h2 ? pv.z : vy2;  ey2 = h2 ? e2 : ey2;
            y3 = h3 ? c : y3;  vy3 = h3 ? pv.w : vy3;  ey3 = h3 ? e3 : ey3;
        }
    }

    // rv = (1 - p_y)^2 * log p_y ;  p_y = e_y / s ;  log p_y = v_y - log s
    {
        const float l0 = vy0 - __logf(s0), p0 = ey0 / s0, o0 = 1.f - p0;
        const float l1 = vy1 - __logf(s1), p1 = ey1 / s1, o1 = 1.f - p1;
        const float l2 = vy2 - __logf(s2), p2 = ey2 / s2, o2 = 1.f - p2;
        const float l3 = vy3 - __logf(s3), p3 = ey3 / s3, o3 = 1.f - p3;
        atomicAdd(&ls_sum[y0], o0 * o0 * l0);  atomicAdd(&ls_cnt[y0], 1.f);
        atomicAdd(&ls_sum[y1], o1 * o1 * l1);  atomicAdd(&ls_cnt[y1], 1.f);
        atomicAdd(&ls_sum[y2], o2 * o2 * l2);  atomicAdd(&ls_cnt[y2], 1.f);
        atomicAdd(&ls_sum[y3], o3 * o3 * l3);  atomicAdd(&ls_cnt[y3], 1.f);
    }
    __syncthreads();
    if (threadIdx.x < CCH) {
        atomicAdd(&gsum[threadIdx.x], ls_sum[threadIdx.x]);
        atomicAdd(&gcnt[threadIdx.x], ls_cnt[threadIdx.x]);
    }
}

// ---------------------------------------------------------------------------
// Kernel 2: one wave. Class-balanced weights + final scalar, in double.
// ---------------------------------------------------------------------------
__global__ void cb_focal_final(const float* __restrict__ gsum,
                               const float* __restrict__ gcnt,
                               float* __restrict__ out)
{
    const int lane = threadIdx.x;
    double term = 0.0;
    if (lane < CCH) {
        const double n    = (double)NPIX;
        const double beta = (n - 1.0) / n;
        const double w = (1.0 - beta) / (1.0 - pow(beta, (double)gcnt[lane]) + 1e-6);
        term = w * (double)gsum[lane];
    }
    for (int off = 32; off; off >>= 1) term += __shfl_down(term, off, 64);
    if (lane == 0) out[0] = (float)(-term / (double)NPIX);
}

// ---------------------------------------------------------------------------
extern "C" void kernel_launch(void* const* d_in, const int* in_sizes, int n_in,
                              void* d_out, int out_size, void* d_ws, size_t ws_size,
                              hipStream_t stream) {
    const float* pred = (const float*)d_in[0];
    const float* targ = (const float*)d_in[1];
    float* out  = (float*)d_out;
    float* gsum = (float*)d_ws;          // [21]
    float* gcnt = gsum + CCH;            // [21]

    (void)hipMemsetAsync(gsum, 0, 2 * CCH * sizeof(float), stream);
    cb_focal_partial<<<NBLK, BLKT, 0, stream>>>(pred, targ, gsum, gcnt);
    cb_focal_final<<<1, 64, 0, stream>>>(gsum, gcnt, out);
}